// Round 14
// baseline (1276.444 us; speedup 1.0000x reference)
//
#include <hip/hip_runtime.h>
#include <hip/hip_bf16.h>

#define NN 200000
#define NE 600000
#define NG 10000
#define NCH 98      // scan chunks of 2048 covering NN
#define NTILE 3125  // 64-row tiles (FIRST layer)
#define NT2 1563    // 128-row tiles (layers 1..4; last tile is half)

typedef __attribute__((ext_vector_type(8))) short bfrag;
typedef __attribute__((ext_vector_type(4))) float f32x4;
typedef unsigned short u16;

static __device__ __forceinline__ u16 f2b(float x) {
  __hip_bfloat16 b = __float2bfloat16(x);
  return __builtin_bit_cast(u16, b);
}
static __device__ __forceinline__ float b2f(u16 u) {
  __hip_bfloat16 b = __builtin_bit_cast(__hip_bfloat16, u);
  return __bfloat162float(b);
}
static __device__ __forceinline__ void split(float v, u16& hi, u16& lo) {
  hi = f2b(v);
  lo = f2b(v - b2f(hi));
}

// ---------------- weight prep: per-lane MFMA B-fragments, bf16 hi+lo ------
__global__ void prep_kernel(const float* __restrict__ W1_0, const float* __restrict__ W2_0,
                            const float* __restrict__ W1s, const float* __restrict__ W2s,
                            u16* __restrict__ wf) {
  int i = blockIdx.x * 256 + threadIdx.x;
  if (i >= 312 * 64) return;
  int t = i >> 6, lane = i & 63;
  const float* W;
  int KS, ct, kk, Krows, base, half;
  if (t < 24) {
    W = W1_0; KS = 3; ct = t / 3; kk = t - ct * 3; Krows = 78; base = 0; half = 12288;
  } else if (t < 56) {
    int u = t - 24;
    W = W2_0; KS = 4; ct = u >> 2; kk = u & 3; Krows = 128; base = 24576; half = 16384;
  } else {
    int u = t - 56;
    int j = u >> 6, r = u & 63;
    KS = 4; Krows = 128; half = 16384;
    if (r < 32) {
      W = W1s + j * 16384; ct = r >> 2; kk = r & 3; base = 57344 + j * 65536;
    } else {
      W = W2s + j * 16384; r -= 32; ct = r >> 2; kk = r & 3; base = 57344 + j * 65536 + 32768;
    }
  }
  int col = ct * 16 + (lane & 15);
  int idx = ((ct * KS + kk) * 64 + lane) * 8;
  for (int jj = 0; jj < 8; jj++) {
    int k = kk * 32 + 8 * (lane >> 4) + jj;
    float v = (k < Krows) ? W[k * 128 + col] : 0.f;
    u16 hi, lo;
    split(v, hi, lo);
    wf[base + idx + jj] = hi;
    wf[base + half + idx + jj] = lo;
  }
}

// ---------------- CSR build: histogram + scan + scatter -------------------
__global__ void hist_kernel(const int* __restrict__ dst, int* __restrict__ deg) {
  int e = blockIdx.x * 256 + threadIdx.x;
  if (e < NE) atomicAdd(&deg[dst[e]], 1);
}

__global__ void scan1_kernel(const int* __restrict__ deg, int* __restrict__ csum) {
  __shared__ int s[256];
  int base = blockIdx.x * 2048 + threadIdx.x * 8;
  int t = 0;
#pragma unroll
  for (int j = 0; j < 8; j++) {
    int idx = base + j;
    if (idx < NN) t += deg[idx];
  }
  s[threadIdx.x] = t;
  __syncthreads();
  for (int o = 128; o > 0; o >>= 1) {
    if (threadIdx.x < o) s[threadIdx.x] += s[threadIdx.x + o];
    __syncthreads();
  }
  if (threadIdx.x == 0) csum[blockIdx.x] = s[0];
}

__global__ void scan2_kernel(int* __restrict__ csum, int* __restrict__ rowptr) {
  int acc = 0;
  for (int i = 0; i < NCH; i++) {
    int v = csum[i];
    csum[i] = acc;
    acc += v;
  }
  rowptr[NN] = acc;  // == NE
}

// NOTE: deg and cursor may alias (each index read-then-written by one thread).
__global__ void scan3_kernel(const int* deg, const int* __restrict__ csum,
                             int* __restrict__ rowptr, int* cursor) {
  __shared__ int s[256];
  int tid = threadIdx.x;
  int base = blockIdx.x * 2048 + tid * 8;
  int loc[8];
  int t = 0;
#pragma unroll
  for (int j = 0; j < 8; j++) {
    int idx = base + j;
    int d = (idx < NN) ? deg[idx] : 0;
    loc[j] = t;
    t += d;
  }
  s[tid] = t;
  __syncthreads();
  for (int o = 1; o < 256; o <<= 1) {
    int u = (tid >= o) ? s[tid - o] : 0;
    __syncthreads();
    s[tid] += u;
    __syncthreads();
  }
  int off = csum[blockIdx.x] + s[tid] - t;
#pragma unroll
  for (int j = 0; j < 8; j++) {
    int idx = base + j;
    if (idx < NN) {
      int r = off + loc[j];
      rowptr[idx] = r;
      cursor[idx] = r;
    }
  }
}

__global__ void scatter_kernel(const int* __restrict__ src, const int* __restrict__ dst,
                               int* __restrict__ cursor, int* __restrict__ csr_src) {
  int e = blockIdx.x * 256 + threadIdx.x;
  if (e < NE) {
    int p = atomicAdd(&cursor[dst[e]], 1);
    csr_src[p] = src[e];
  }
}

// ---------------- layer 0: proven R9 block-synchronous path ---------------
__global__ __launch_bounds__(512, 4) void first_kernel(
    const float* __restrict__ xin,
    const int* __restrict__ rowptr, const int* __restrict__ csr_src,
    const u16* __restrict__ w1hi, const u16* __restrict__ w1lo,
    const u16* __restrict__ w2hi, const u16* __restrict__ w2lo,
    const float* __restrict__ b1, const float* __restrict__ b2,
    u16* __restrict__ hout, float* __restrict__ stats) {
  constexpr int KS1 = 3;
  constexpr int AH = 0, AL = 8704, TH = 17408, TL = 26112;
  __shared__ u16 lds[34816];
  const int tid = threadIdx.x;
  const int w = tid >> 6, l = tid & 63;
  const int l15 = l & 15, lg = l >> 4;
  const float bb1 = b1[w * 16 + l15];
  const float bb2 = b2[w * 16 + l15];
  float s_acc = 0.f, q_acc = 0.f;

  const float2* x2 = reinterpret_cast<const float2*>(xin);
  for (int tile = blockIdx.x; tile < NTILE; tile += gridDim.x) {
    const int rows0 = tile * 64;
    for (int j = 0; j < 8; j++) {
      int row = w * 8 + j;
      int node = rows0 + row;
      int beg = rowptr[node], end = rowptr[node + 1];
      int f0 = l * 2;
      if (f0 < 78) {
        size_t fv = (size_t)(f0 >> 1);
        float2 acc = x2[(size_t)node * 39 + fv];
        for (int i = beg; i < end; i += 4) {
          int last = end - 1;
          int i1 = min(i + 1, last), i2 = min(i + 2, last), i3 = min(i + 3, last);
          int s0 = csr_src[i], s1 = csr_src[i1], s2 = csr_src[i2], s3 = csr_src[i3];
          float2 v0 = x2[(size_t)s0 * 39 + fv];
          float2 v1 = x2[(size_t)s1 * 39 + fv];
          float2 v2 = x2[(size_t)s2 * 39 + fv];
          float2 v3 = x2[(size_t)s3 * 39 + fv];
          int rem = end - i;
          float m1 = rem > 1 ? 1.f : 0.f, m2 = rem > 2 ? 1.f : 0.f, m3 = rem > 3 ? 1.f : 0.f;
          acc.x += v0.x + m1 * v1.x + m2 * v2.x + m3 * v3.x;
          acc.y += v0.y + m1 * v1.y + m2 * v2.y + m3 * v3.y;
        }
        ushort2 oh, ol;
        split(acc.x, oh.x, ol.x);
        split(acc.y, oh.y, ol.y);
        *reinterpret_cast<ushort2*>(&lds[AH + row * 136 + f0]) = oh;
        *reinterpret_cast<ushort2*>(&lds[AL + row * 136 + f0]) = ol;
      } else if (f0 < 96) {
        ushort2 z = {0, 0};
        *reinterpret_cast<ushort2*>(&lds[AH + row * 136 + f0]) = z;
        *reinterpret_cast<ushort2*>(&lds[AL + row * 136 + f0]) = z;
      }
    }
    bfrag w1h[KS1], w1l[KS1];
#pragma unroll
    for (int kk = 0; kk < KS1; kk++) {
      int fi = ((w * KS1 + kk) * 64 + l) * 8;
      w1h[kk] = *reinterpret_cast<const bfrag*>(&w1hi[fi]);
      w1l[kk] = *reinterpret_cast<const bfrag*>(&w1lo[fi]);
    }
    __syncthreads();
#pragma unroll
    for (int rt = 0; rt < 4; rt++) {
      f32x4 acc = {bb1, bb1, bb1, bb1};
      const int arow = (rt * 16 + l15) * 136 + 8 * lg;
#pragma unroll
      for (int kk = 0; kk < KS1; kk++) {
        bfrag ah = *reinterpret_cast<const bfrag*>(&lds[AH + arow + kk * 32]);
        bfrag al = *reinterpret_cast<const bfrag*>(&lds[AL + arow + kk * 32]);
        acc = __builtin_amdgcn_mfma_f32_16x16x32_bf16(al, w1h[kk], acc, 0, 0, 0);
        acc = __builtin_amdgcn_mfma_f32_16x16x32_bf16(ah, w1l[kk], acc, 0, 0, 0);
        acc = __builtin_amdgcn_mfma_f32_16x16x32_bf16(ah, w1h[kk], acc, 0, 0, 0);
      }
#pragma unroll
      for (int r = 0; r < 4; r++) {
        float v = fmaxf(acc[r], 0.f);
        u16 hi, lo;
        split(v, hi, lo);
        int off = (rt * 16 + 4 * lg + r) * 136 + w * 16 + l15;
        lds[TH + off] = hi;
        lds[TL + off] = lo;
      }
    }
    bfrag w2h[4], w2l[4];
#pragma unroll
    for (int kk = 0; kk < 4; kk++) {
      int fi = ((w * 4 + kk) * 64 + l) * 8;
      w2h[kk] = *reinterpret_cast<const bfrag*>(&w2hi[fi]);
      w2l[kk] = *reinterpret_cast<const bfrag*>(&w2lo[fi]);
    }
    __syncthreads();
    u16 o16[16];
#pragma unroll
    for (int rt = 0; rt < 4; rt++) {
      f32x4 acc = {bb2, bb2, bb2, bb2};
      const int arow = (rt * 16 + l15) * 136 + 8 * lg;
#pragma unroll
      for (int kk = 0; kk < 4; kk++) {
        bfrag th = *reinterpret_cast<const bfrag*>(&lds[TH + arow + kk * 32]);
        bfrag tl = *reinterpret_cast<const bfrag*>(&lds[TL + arow + kk * 32]);
        acc = __builtin_amdgcn_mfma_f32_16x16x32_bf16(tl, w2h[kk], acc, 0, 0, 0);
        acc = __builtin_amdgcn_mfma_f32_16x16x32_bf16(th, w2l[kk], acc, 0, 0, 0);
        acc = __builtin_amdgcn_mfma_f32_16x16x32_bf16(th, w2h[kk], acc, 0, 0, 0);
      }
#pragma unroll
      for (int r = 0; r < 4; r++) {
        float v = fmaxf(acc[r], 0.f);
        s_acc += v;
        q_acc += v * v;
        o16[rt * 4 + r] = f2b(v);
      }
    }
    __syncthreads();
#pragma unroll
    for (int rt = 0; rt < 4; rt++)
#pragma unroll
      for (int r = 0; r < 4; r++)
        lds[TH + (rt * 16 + 4 * lg + r) * 136 + w * 16 + l15] = o16[rt * 4 + r];
    __syncthreads();
#pragma unroll
    for (int p2 = 0; p2 < 2; p2++) {
      int row = p2 * 32 + (tid >> 4);
      int c8 = tid & 15;
      bfrag vv = *reinterpret_cast<const bfrag*>(&lds[TH + row * 136 + c8 * 8]);
      *reinterpret_cast<bfrag*>(&hout[(size_t)(rows0 + row) * 128 + c8 * 8]) = vv;
    }
    __syncthreads();
  }
  s_acc += __shfl_xor(s_acc, 16);
  s_acc += __shfl_xor(s_acc, 32);
  q_acc += __shfl_xor(q_acc, 16);
  q_acc += __shfl_xor(q_acc, 32);
  if (lg == 0) {
    atomicAdd(&stats[w * 16 + l15], s_acc);
    atomicAdd(&stats[128 + w * 16 + l15], q_acc);
  }
}

// ---------------- layers 1..4: 16-wave 128-row tiles ----------------------
// Same per-thread code shape as R9 (VGPR 64, no spill) but 1024 threads:
// 16 waves stage concurrently -> 2x outstanding gather requests at the SAME
// 2-blocks/CU residency (more waves, not more blocks -> tests the thrash
// mechanism). Wave w: stages rows [w*8,w*8+8); GEMMs ct=w&7 on row-half
// (w>>3)*64. LDS 69.6 KB, A -> T -> OUT overlaid. Tail tile (64 valid
// rows) handled by zero-staging + masked stats + guarded writes.
__global__ __launch_bounds__(1024, 8) void gin_kernel(
    const u16* __restrict__ hin, const float* __restrict__ ss,
    const int* __restrict__ rowptr, const int* __restrict__ csr_src,
    const u16* __restrict__ w1hi, const u16* __restrict__ w1lo,
    const u16* __restrict__ w2hi, const u16* __restrict__ w2lo,
    const float* __restrict__ b1, const float* __restrict__ b2,
    u16* __restrict__ hout, float* __restrict__ stats) {
  constexpr int AH = 0, AL = 17408;  // u16 offsets; 128 rows x 136 each
  __shared__ u16 lds[34816];         // 69,632 B
  const int tid = threadIdx.x;
  const int w = tid >> 6, l = tid & 63;
  const int l15 = l & 15, lg = l >> 4;
  const int ct = w & 7;
  const int hrow = (w >> 3) * 64;
  const float bb1 = b1[ct * 16 + l15];
  const float bb2 = b2[ct * 16 + l15];
  const bfrag* hp = reinterpret_cast<const bfrag*>(hin);
  const int k8v = l15;
  const int k8 = l15 * 8;
  float sc8[8], sh8[8];
#pragma unroll
  for (int j = 0; j < 8; j++) {
    sc8[j] = ss[k8 + j];
    sh8[j] = ss[128 + k8 + j];
  }
  float s_acc = 0.f, q_acc = 0.f;

  for (int tile = blockIdx.x; tile < NT2; tile += gridDim.x) {
    const int rows0 = tile * 128;

    // ---- stage A: 16 waves x 8 rows (masked chunk-of-4 gather) ----
    for (int p = 0; p < 2; p++) {
      int row = w * 8 + p * 4 + lg;
      int node = rows0 + row;
      bfrag oh, ol;
      if (node < NN) {
        int beg = rowptr[node], end = rowptr[node + 1];
        float a[8];
        bfrag vs = hp[(size_t)node * 16 + k8v];  // self
#pragma unroll
        for (int j = 0; j < 8; j++) a[j] = b2f((u16)vs[j]);
        for (int i = beg; i < end; i += 4) {
          int last = end - 1;
          int i1 = min(i + 1, last), i2 = min(i + 2, last), i3 = min(i + 3, last);
          int s0 = csr_src[i], s1 = csr_src[i1], s2 = csr_src[i2], s3 = csr_src[i3];
          bfrag v0 = hp[(size_t)s0 * 16 + k8v];
          bfrag v1 = hp[(size_t)s1 * 16 + k8v];
          bfrag v2 = hp[(size_t)s2 * 16 + k8v];
          bfrag v3 = hp[(size_t)s3 * 16 + k8v];
          int rem = end - i;
          float m1 = rem > 1 ? 1.f : 0.f, m2 = rem > 2 ? 1.f : 0.f, m3 = rem > 3 ? 1.f : 0.f;
#pragma unroll
          for (int j = 0; j < 8; j++)
            a[j] += (b2f((u16)v0[j]) + m1 * b2f((u16)v1[j])) +
                    (m2 * b2f((u16)v2[j]) + m3 * b2f((u16)v3[j]));
        }
        float cnt = (float)(end - beg + 1);
#pragma unroll
        for (int j = 0; j < 8; j++) {
          float t = a[j] * sc8[j] + cnt * sh8[j];
          u16 hi, lo;
          split(t, hi, lo);
          oh[j] = (short)hi;
          ol[j] = (short)lo;
        }
      } else {
#pragma unroll
        for (int j = 0; j < 8; j++) { oh[j] = 0; ol[j] = 0; }
      }
      *reinterpret_cast<bfrag*>(&lds[AH + row * 136 + k8]) = oh;
      *reinterpret_cast<bfrag*>(&lds[AL + row * 136 + k8]) = ol;
    }
    // ---- W1 frags for this wave's ct ----
    bfrag w1h[4], w1l[4];
#pragma unroll
    for (int kk = 0; kk < 4; kk++) {
      int fi = ((ct * 4 + kk) * 64 + l) * 8;
      w1h[kk] = *reinterpret_cast<const bfrag*>(&w1hi[fi]);
      w1l[kk] = *reinterpret_cast<const bfrag*>(&w1lo[fi]);
    }
    __syncthreads();  // B1: A staged

    // ---- GEMM1 (accs in regs; A region stays live) ----
    f32x4 t1[4];
#pragma unroll
    for (int rt = 0; rt < 4; rt++) {
      f32x4 acc = {bb1, bb1, bb1, bb1};
      const int arow = (hrow + rt * 16 + l15) * 136 + 8 * lg;
#pragma unroll
      for (int kk = 0; kk < 4; kk++) {
        bfrag ah = *reinterpret_cast<const bfrag*>(&lds[AH + arow + kk * 32]);
        bfrag al = *reinterpret_cast<const bfrag*>(&lds[AL + arow + kk * 32]);
        acc = __builtin_amdgcn_mfma_f32_16x16x32_bf16(al, w1h[kk], acc, 0, 0, 0);
        acc = __builtin_amdgcn_mfma_f32_16x16x32_bf16(ah, w1l[kk], acc, 0, 0, 0);
        acc = __builtin_amdgcn_mfma_f32_16x16x32_bf16(ah, w1h[kk], acc, 0, 0, 0);
      }
      t1[rt] = acc;
    }
    __syncthreads();  // B2: A dead -> region reusable for T

    // ---- write T (relu+split) over A region ----
#pragma unroll
    for (int rt = 0; rt < 4; rt++) {
#pragma unroll
      for (int r = 0; r < 4; r++) {
        float v = fmaxf(t1[rt][r], 0.f);
        u16 hi, lo;
        split(v, hi, lo);
        int off = (hrow + rt * 16 + 4 * lg + r) * 136 + ct * 16 + l15;
        lds[AH + off] = hi;
        lds[AL + off] = lo;
      }
    }
    bfrag w2h[4], w2l[4];
#pragma unroll
    for (int kk = 0; kk < 4; kk++) {
      int fi = ((ct * 4 + kk) * 64 + l) * 8;
      w2h[kk] = *reinterpret_cast<const bfrag*>(&w2hi[fi]);
      w2l[kk] = *reinterpret_cast<const bfrag*>(&w2lo[fi]);
    }
    __syncthreads();  // B3: T visible

    // ---- GEMM2 ----
    u16 o16[16];
#pragma unroll
    for (int rt = 0; rt < 4; rt++) {
      f32x4 acc = {bb2, bb2, bb2, bb2};
      const int arow = (hrow + rt * 16 + l15) * 136 + 8 * lg;
#pragma unroll
      for (int kk = 0; kk < 4; kk++) {
        bfrag th = *reinterpret_cast<const bfrag*>(&lds[AH + arow + kk * 32]);
        bfrag tl = *reinterpret_cast<const bfrag*>(&lds[AL + arow + kk * 32]);
        acc = __builtin_amdgcn_mfma_f32_16x16x32_bf16(tl, w2h[kk], acc, 0, 0, 0);
        acc = __builtin_amdgcn_mfma_f32_16x16x32_bf16(th, w2l[kk], acc, 0, 0, 0);
        acc = __builtin_amdgcn_mfma_f32_16x16x32_bf16(th, w2h[kk], acc, 0, 0, 0);
      }
#pragma unroll
      for (int r = 0; r < 4; r++) {
        float v = fmaxf(acc[r], 0.f);
        int gr = rows0 + hrow + rt * 16 + 4 * lg + r;
        if (gr < NN) {  // tail tile: exclude garbage rows from BN stats
          s_acc += v;
          q_acc += v * v;
        }
        o16[rt * 4 + r] = f2b(v);
      }
    }
    __syncthreads();  // B4: T dead -> region reusable for OUT

    // ---- stage OUT (bf16) ----
#pragma unroll
    for (int rt = 0; rt < 4; rt++)
#pragma unroll
      for (int r = 0; r < 4; r++)
        lds[AH + (hrow + rt * 16 + 4 * lg + r) * 136 + ct * 16 + l15] = o16[rt * 4 + r];
    __syncthreads();  // B5: OUT staged

    // ---- cooperative full-row write: 64 rows/pass x 256B ----
#pragma unroll
    for (int p2 = 0; p2 < 2; p2++) {
      int row = p2 * 64 + (tid >> 4);
      int c8 = tid & 15;
      int gr = rows0 + row;
      if (gr < NN) {
        bfrag vv = *reinterpret_cast<const bfrag*>(&lds[AH + row * 136 + c8 * 8]);
        *reinterpret_cast<bfrag*>(&hout[(size_t)gr * 128 + c8 * 8]) = vv;
      }
    }
    __syncthreads();  // B6: protect region before next staging
  }
  // ---- flush BN stats (2 waves per ct -> 2 atomics per ct) ----
  s_acc += __shfl_xor(s_acc, 16);
  s_acc += __shfl_xor(s_acc, 32);
  q_acc += __shfl_xor(q_acc, 16);
  q_acc += __shfl_xor(q_acc, 32);
  if (lg == 0) {
    atomicAdd(&stats[ct * 16 + l15], s_acc);
    atomicAdd(&stats[128 + ct * 16 + l15], q_acc);
  }
}

// ---------------- BN finalize -------------------------------------------
__global__ void bn_kernel(const float* __restrict__ stats, const float* __restrict__ gamma,
                          const float* __restrict__ beta, float* __restrict__ ss) {
  int c = threadIdx.x;  // 128 threads
  float mean = stats[c] * (1.f / NN);
  float var = stats[128 + c] * (1.f / NN) - mean * mean;
  var = fmaxf(var, 0.f);
  float sc = gamma[c] * rsqrtf(var + 1e-5f);
  ss[c] = sc;
  ss[128 + c] = beta[c] - mean * sc;
}

// ---------------- pooling: run-based segmented sum (batch is sorted) ------
__global__ void pool_kernel(const u16* __restrict__ h, const float* __restrict__ ss,
                            const int* __restrict__ batch, float* __restrict__ pooled) {
  int c = threadIdx.x;  // 128 threads, one feature each
  int n0 = blockIdx.x * 128;
  int n1 = min(n0 + 128, NN);
  float sc = ss[c], sh = ss[128 + c];
  float acc = 0.f;
  float cnt = 0.f;
  int gprev = batch[n0];
  for (int n = n0; n < n1; n++) {
    int g = batch[n];
    if (g != gprev) {
      atomicAdd(&pooled[gprev * 128 + c], sc * acc + cnt * sh);
      acc = 0.f;
      cnt = 0.f;
      gprev = g;
    }
    acc += b2f(h[(size_t)n * 128 + c]);
    cnt += 1.f;
  }
  atomicAdd(&pooled[gprev * 128 + c], sc * acc + cnt * sh);
}

// ---------------- final FC ------------------------------------------------
__global__ void fc_kernel(const float* __restrict__ pooled, const float* __restrict__ fcW,
                          const float* __restrict__ fcb, float* __restrict__ out) {
  int i = blockIdx.x * 256 + threadIdx.x;
  if (i >= NG * 64) return;
  int g = i >> 6, o = i & 63;
  float acc = fcb[o];
#pragma unroll 8
  for (int k = 0; k < 128; k++) acc += pooled[g * 128 + k] * fcW[k * 64 + o];
  out[i] = fmaxf(acc, 0.f);
}

extern "C" void kernel_launch(void* const* d_in, const int* in_sizes, int n_in,
                              void* d_out, int out_size, void* d_ws, size_t ws_size,
                              hipStream_t stream) {
  const float* x = (const float*)d_in[0];
  const int* ei = (const int*)d_in[1];
  const int* src = ei;
  const int* dst = ei + NE;
  const int* batch = (const int*)d_in[2];
  const float* W1_0 = (const float*)d_in[3];
  const float* b1_0 = (const float*)d_in[4];
  const float* W2_0 = (const float*)d_in[5];
  const float* b2_0 = (const float*)d_in[6];
  const float* g_0 = (const float*)d_in[7];
  const float* be_0 = (const float*)d_in[8];
  const float* W1s = (const float*)d_in[9];
  const float* b1s = (const float*)d_in[10];
  const float* W2s = (const float*)d_in[11];
  const float* b2s = (const float*)d_in[12];
  const float* gs = (const float*)d_in[13];
  const float* bes = (const float*)d_in[14];
  const float* fcW = (const float*)d_in[15];
  const float* fcb = (const float*)d_in[16];

  char* ws = (char*)d_ws;
  u16* buf0 = (u16*)(ws + 0);                       // 51,200,000 B
  u16* buf1 = (u16*)(ws + 51200000);                // 51,200,000 B
  float* POOLED = (float*)(ws + 102400000);         // 5,120,000 B
  float* STATS = (float*)(ws + 107520000);          // 1,024 B
  float* SS = (float*)(ws + 107521024);             // 1,024 B
  u16* WF = (u16*)(ws + 107522048);                 // 638,976 B
  int* ROWPTR = (int*)(ws + 108161024);             // 800,016 B
  int* CURSOR = (int*)(ws + 108961040);             // 800,000 B (also deg scratch)
  int* CSRC = (int*)(ws + 109761040);               // 2,400,000 B
  int* CSUM = (int*)(ws + 112161040);               // 512 B

  prep_kernel<<<78, 256, 0, stream>>>(W1_0, W2_0, W1s, W2s, WF);

  // ---- CSR build (once per launch; reused by all 5 layers) ----
  hipMemsetAsync(CURSOR, 0, NN * 4, stream);
  hist_kernel<<<(NE + 255) / 256, 256, 0, stream>>>(dst, CURSOR);
  scan1_kernel<<<NCH, 256, 0, stream>>>(CURSOR, CSUM);
  scan2_kernel<<<1, 1, 0, stream>>>(CSUM, ROWPTR);
  scan3_kernel<<<NCH, 256, 0, stream>>>(CURSOR, CSUM, ROWPTR, CURSOR);
  scatter_kernel<<<(NE + 255) / 256, 256, 0, stream>>>(src, dst, CURSOR, CSRC);

  u16* buf[2] = {buf0, buf1};
  // ---- layer 0: x -> buf0 ----
  hipMemsetAsync(STATS, 0, 1024, stream);
  first_kernel<<<512, 512, 0, stream>>>(x, ROWPTR, CSRC,
                                        WF, WF + 12288, WF + 24576, WF + 40960,
                                        b1_0, b2_0, buf0, STATS);
  bn_kernel<<<1, 128, 0, stream>>>(STATS, g_0, be_0, SS);

  // ---- layers 1..4: ping-pong buf0 <-> buf1 ----
  for (int L = 1; L < 5; L++) {
    int j = L - 1;
    const u16* hin = buf[(L + 1) & 1];
    u16* hb = buf[L & 1];
    hipMemsetAsync(STATS, 0, 1024, stream);
    const u16* wl = WF + 57344 + j * 65536;
    gin_kernel<<<512, 1024, 0, stream>>>(hin, SS, ROWPTR, CSRC,
                                         wl, wl + 16384, wl + 32768, wl + 49152,
                                         b1s + j * 128, b2s + j * 128, hb, STATS);
    bn_kernel<<<1, 128, 0, stream>>>(STATS, gs + j * 128, bes + j * 128, SS);
  }

  hipMemsetAsync(POOLED, 0, (size_t)NG * 128 * 4, stream);
  pool_kernel<<<(NN + 127) / 128, 128, 0, stream>>>(buf[0], SS, batch, POOLED);
  fc_kernel<<<(NG * 64 + 255) / 256, 256, 0, stream>>>(POOLED, fcW, fcb, (float*)d_out);
}

// Round 15
// 830.469 us; speedup vs baseline: 1.5370x; 1.5370x over previous
//
#include <hip/hip_runtime.h>
#include <hip/hip_bf16.h>

#define NN 200000
#define NE 600000
#define NG 10000
#define NCH 98      // scan chunks of 2048 covering NN
#define NTILE 3125  // 64-row tiles (FIRST layer)
#define NT2 1563    // 128-row tiles (layers 1..4; last tile is half)

typedef __attribute__((ext_vector_type(8))) short bfrag;
typedef __attribute__((ext_vector_type(4))) float f32x4;
typedef unsigned short u16;

static __device__ __forceinline__ u16 f2b(float x) {
  __hip_bfloat16 b = __float2bfloat16(x);
  return __builtin_bit_cast(u16, b);
}
static __device__ __forceinline__ float b2f(u16 u) {
  __hip_bfloat16 b = __builtin_bit_cast(__hip_bfloat16, u);
  return __bfloat162float(b);
}
static __device__ __forceinline__ void split(float v, u16& hi, u16& lo) {
  hi = f2b(v);
  lo = f2b(v - b2f(hi));
}

// ---------------- weight prep: per-lane MFMA B-fragments, bf16 hi+lo ------
__global__ void prep_kernel(const float* __restrict__ W1_0, const float* __restrict__ W2_0,
                            const float* __restrict__ W1s, const float* __restrict__ W2s,
                            u16* __restrict__ wf) {
  int i = blockIdx.x * 256 + threadIdx.x;
  if (i >= 312 * 64) return;
  int t = i >> 6, lane = i & 63;
  const float* W;
  int KS, ct, kk, Krows, base, half;
  if (t < 24) {
    W = W1_0; KS = 3; ct = t / 3; kk = t - ct * 3; Krows = 78; base = 0; half = 12288;
  } else if (t < 56) {
    int u = t - 24;
    W = W2_0; KS = 4; ct = u >> 2; kk = u & 3; Krows = 128; base = 24576; half = 16384;
  } else {
    int u = t - 56;
    int j = u >> 6, r = u & 63;
    KS = 4; Krows = 128; half = 16384;
    if (r < 32) {
      W = W1s + j * 16384; ct = r >> 2; kk = r & 3; base = 57344 + j * 65536;
    } else {
      W = W2s + j * 16384; r -= 32; ct = r >> 2; kk = r & 3; base = 57344 + j * 65536 + 32768;
    }
  }
  int col = ct * 16 + (lane & 15);
  int idx = ((ct * KS + kk) * 64 + lane) * 8;
  for (int jj = 0; jj < 8; jj++) {
    int k = kk * 32 + 8 * (lane >> 4) + jj;
    float v = (k < Krows) ? W[k * 128 + col] : 0.f;
    u16 hi, lo;
    split(v, hi, lo);
    wf[base + idx + jj] = hi;
    wf[base + half + idx + jj] = lo;
  }
}

// ---------------- CSR build: histogram + scan + scatter -------------------
__global__ void hist_kernel(const int* __restrict__ dst, int* __restrict__ deg) {
  int e = blockIdx.x * 256 + threadIdx.x;
  if (e < NE) atomicAdd(&deg[dst[e]], 1);
}

__global__ void scan1_kernel(const int* __restrict__ deg, int* __restrict__ csum) {
  __shared__ int s[256];
  int base = blockIdx.x * 2048 + threadIdx.x * 8;
  int t = 0;
#pragma unroll
  for (int j = 0; j < 8; j++) {
    int idx = base + j;
    if (idx < NN) t += deg[idx];
  }
  s[threadIdx.x] = t;
  __syncthreads();
  for (int o = 128; o > 0; o >>= 1) {
    if (threadIdx.x < o) s[threadIdx.x] += s[threadIdx.x + o];
    __syncthreads();
  }
  if (threadIdx.x == 0) csum[blockIdx.x] = s[0];
}

__global__ void scan2_kernel(int* __restrict__ csum, int* __restrict__ rowptr) {
  int acc = 0;
  for (int i = 0; i < NCH; i++) {
    int v = csum[i];
    csum[i] = acc;
    acc += v;
  }
  rowptr[NN] = acc;  // == NE
}

// NOTE: deg and cursor may alias (each index read-then-written by one thread).
__global__ void scan3_kernel(const int* deg, const int* __restrict__ csum,
                             int* __restrict__ rowptr, int* cursor) {
  __shared__ int s[256];
  int tid = threadIdx.x;
  int base = blockIdx.x * 2048 + tid * 8;
  int loc[8];
  int t = 0;
#pragma unroll
  for (int j = 0; j < 8; j++) {
    int idx = base + j;
    int d = (idx < NN) ? deg[idx] : 0;
    loc[j] = t;
    t += d;
  }
  s[tid] = t;
  __syncthreads();
  for (int o = 1; o < 256; o <<= 1) {
    int u = (tid >= o) ? s[tid - o] : 0;
    __syncthreads();
    s[tid] += u;
    __syncthreads();
  }
  int off = csum[blockIdx.x] + s[tid] - t;
#pragma unroll
  for (int j = 0; j < 8; j++) {
    int idx = base + j;
    if (idx < NN) {
      int r = off + loc[j];
      rowptr[idx] = r;
      cursor[idx] = r;
    }
  }
}

__global__ void scatter_kernel(const int* __restrict__ src, const int* __restrict__ dst,
                               int* __restrict__ cursor, int* __restrict__ csr_src) {
  int e = blockIdx.x * 256 + threadIdx.x;
  if (e < NE) {
    int p = atomicAdd(&cursor[dst[e]], 1);
    csr_src[p] = src[e];
  }
}

// ---------------- layer 0: proven R9 block-synchronous path ---------------
__global__ __launch_bounds__(512, 4) void first_kernel(
    const float* __restrict__ xin,
    const int* __restrict__ rowptr, const int* __restrict__ csr_src,
    const u16* __restrict__ w1hi, const u16* __restrict__ w1lo,
    const u16* __restrict__ w2hi, const u16* __restrict__ w2lo,
    const float* __restrict__ b1, const float* __restrict__ b2,
    u16* __restrict__ hout, float* __restrict__ stats) {
  constexpr int KS1 = 3;
  constexpr int AH = 0, AL = 8704, TH = 17408, TL = 26112;
  __shared__ u16 lds[34816];
  const int tid = threadIdx.x;
  const int w = tid >> 6, l = tid & 63;
  const int l15 = l & 15, lg = l >> 4;
  const float bb1 = b1[w * 16 + l15];
  const float bb2 = b2[w * 16 + l15];
  float s_acc = 0.f, q_acc = 0.f;

  const float2* x2 = reinterpret_cast<const float2*>(xin);
  for (int tile = blockIdx.x; tile < NTILE; tile += gridDim.x) {
    const int rows0 = tile * 64;
    for (int j = 0; j < 8; j++) {
      int row = w * 8 + j;
      int node = rows0 + row;
      int beg = rowptr[node], end = rowptr[node + 1];
      int f0 = l * 2;
      if (f0 < 78) {
        size_t fv = (size_t)(f0 >> 1);
        float2 acc = x2[(size_t)node * 39 + fv];
        for (int i = beg; i < end; i += 4) {
          int last = end - 1;
          int i1 = min(i + 1, last), i2 = min(i + 2, last), i3 = min(i + 3, last);
          int s0 = csr_src[i], s1 = csr_src[i1], s2 = csr_src[i2], s3 = csr_src[i3];
          float2 v0 = x2[(size_t)s0 * 39 + fv];
          float2 v1 = x2[(size_t)s1 * 39 + fv];
          float2 v2 = x2[(size_t)s2 * 39 + fv];
          float2 v3 = x2[(size_t)s3 * 39 + fv];
          int rem = end - i;
          float m1 = rem > 1 ? 1.f : 0.f, m2 = rem > 2 ? 1.f : 0.f, m3 = rem > 3 ? 1.f : 0.f;
          acc.x += v0.x + m1 * v1.x + m2 * v2.x + m3 * v3.x;
          acc.y += v0.y + m1 * v1.y + m2 * v2.y + m3 * v3.y;
        }
        ushort2 oh, ol;
        split(acc.x, oh.x, ol.x);
        split(acc.y, oh.y, ol.y);
        *reinterpret_cast<ushort2*>(&lds[AH + row * 136 + f0]) = oh;
        *reinterpret_cast<ushort2*>(&lds[AL + row * 136 + f0]) = ol;
      } else if (f0 < 96) {
        ushort2 z = {0, 0};
        *reinterpret_cast<ushort2*>(&lds[AH + row * 136 + f0]) = z;
        *reinterpret_cast<ushort2*>(&lds[AL + row * 136 + f0]) = z;
      }
    }
    bfrag w1h[KS1], w1l[KS1];
#pragma unroll
    for (int kk = 0; kk < KS1; kk++) {
      int fi = ((w * KS1 + kk) * 64 + l) * 8;
      w1h[kk] = *reinterpret_cast<const bfrag*>(&w1hi[fi]);
      w1l[kk] = *reinterpret_cast<const bfrag*>(&w1lo[fi]);
    }
    __syncthreads();
#pragma unroll
    for (int rt = 0; rt < 4; rt++) {
      f32x4 acc = {bb1, bb1, bb1, bb1};
      const int arow = (rt * 16 + l15) * 136 + 8 * lg;
#pragma unroll
      for (int kk = 0; kk < KS1; kk++) {
        bfrag ah = *reinterpret_cast<const bfrag*>(&lds[AH + arow + kk * 32]);
        bfrag al = *reinterpret_cast<const bfrag*>(&lds[AL + arow + kk * 32]);
        acc = __builtin_amdgcn_mfma_f32_16x16x32_bf16(al, w1h[kk], acc, 0, 0, 0);
        acc = __builtin_amdgcn_mfma_f32_16x16x32_bf16(ah, w1l[kk], acc, 0, 0, 0);
        acc = __builtin_amdgcn_mfma_f32_16x16x32_bf16(ah, w1h[kk], acc, 0, 0, 0);
      }
#pragma unroll
      for (int r = 0; r < 4; r++) {
        float v = fmaxf(acc[r], 0.f);
        u16 hi, lo;
        split(v, hi, lo);
        int off = (rt * 16 + 4 * lg + r) * 136 + w * 16 + l15;
        lds[TH + off] = hi;
        lds[TL + off] = lo;
      }
    }
    bfrag w2h[4], w2l[4];
#pragma unroll
    for (int kk = 0; kk < 4; kk++) {
      int fi = ((w * 4 + kk) * 64 + l) * 8;
      w2h[kk] = *reinterpret_cast<const bfrag*>(&w2hi[fi]);
      w2l[kk] = *reinterpret_cast<const bfrag*>(&w2lo[fi]);
    }
    __syncthreads();
    u16 o16[16];
#pragma unroll
    for (int rt = 0; rt < 4; rt++) {
      f32x4 acc = {bb2, bb2, bb2, bb2};
      const int arow = (rt * 16 + l15) * 136 + 8 * lg;
#pragma unroll
      for (int kk = 0; kk < 4; kk++) {
        bfrag th = *reinterpret_cast<const bfrag*>(&lds[TH + arow + kk * 32]);
        bfrag tl = *reinterpret_cast<const bfrag*>(&lds[TL + arow + kk * 32]);
        acc = __builtin_amdgcn_mfma_f32_16x16x32_bf16(tl, w2h[kk], acc, 0, 0, 0);
        acc = __builtin_amdgcn_mfma_f32_16x16x32_bf16(th, w2l[kk], acc, 0, 0, 0);
        acc = __builtin_amdgcn_mfma_f32_16x16x32_bf16(th, w2h[kk], acc, 0, 0, 0);
      }
#pragma unroll
      for (int r = 0; r < 4; r++) {
        float v = fmaxf(acc[r], 0.f);
        s_acc += v;
        q_acc += v * v;
        o16[rt * 4 + r] = f2b(v);
      }
    }
    __syncthreads();
#pragma unroll
    for (int rt = 0; rt < 4; rt++)
#pragma unroll
      for (int r = 0; r < 4; r++)
        lds[TH + (rt * 16 + 4 * lg + r) * 136 + w * 16 + l15] = o16[rt * 4 + r];
    __syncthreads();
#pragma unroll
    for (int p2 = 0; p2 < 2; p2++) {
      int row = p2 * 32 + (tid >> 4);
      int c8 = tid & 15;
      bfrag vv = *reinterpret_cast<const bfrag*>(&lds[TH + row * 136 + c8 * 8]);
      *reinterpret_cast<bfrag*>(&hout[(size_t)(rows0 + row) * 128 + c8 * 8]) = vv;
    }
    __syncthreads();
  }
  s_acc += __shfl_xor(s_acc, 16);
  s_acc += __shfl_xor(s_acc, 32);
  q_acc += __shfl_xor(q_acc, 16);
  q_acc += __shfl_xor(q_acc, 32);
  if (lg == 0) {
    atomicAdd(&stats[w * 16 + l15], s_acc);
    atomicAdd(&stats[128 + w * 16 + l15], q_acc);
  }
}

// ---------------- layers 1..4: 16-wave 128-row tiles ----------------------
// R14 structure with the spill FIXED: __launch_bounds__(1024,4) caps VGPR
// at 128 (code needs ~64, as R9 measured) instead of (1024,8)'s 32-VGPR
// clamp that spilled to scratch (+250MB write, +250MB fetch). Residency is
// still 2 blocks/CU (set by 69.6 KB LDS) = 32 waves/CU; 16 waves stage
// concurrently -> 2x outstanding gather requests vs R9. Tail tile handled
// by zero-staging + masked stats + guarded writes.
__global__ __launch_bounds__(1024, 4) void gin_kernel(
    const u16* __restrict__ hin, const float* __restrict__ ss,
    const int* __restrict__ rowptr, const int* __restrict__ csr_src,
    const u16* __restrict__ w1hi, const u16* __restrict__ w1lo,
    const u16* __restrict__ w2hi, const u16* __restrict__ w2lo,
    const float* __restrict__ b1, const float* __restrict__ b2,
    u16* __restrict__ hout, float* __restrict__ stats) {
  constexpr int AH = 0, AL = 17408;  // u16 offsets; 128 rows x 136 each
  __shared__ u16 lds[34816];         // 69,632 B
  const int tid = threadIdx.x;
  const int w = tid >> 6, l = tid & 63;
  const int l15 = l & 15, lg = l >> 4;
  const int ct = w & 7;
  const int hrow = (w >> 3) * 64;
  const float bb1 = b1[ct * 16 + l15];
  const float bb2 = b2[ct * 16 + l15];
  const bfrag* hp = reinterpret_cast<const bfrag*>(hin);
  const int k8v = l15;
  const int k8 = l15 * 8;
  float sc8[8], sh8[8];
#pragma unroll
  for (int j = 0; j < 8; j++) {
    sc8[j] = ss[k8 + j];
    sh8[j] = ss[128 + k8 + j];
  }
  float s_acc = 0.f, q_acc = 0.f;

  for (int tile = blockIdx.x; tile < NT2; tile += gridDim.x) {
    const int rows0 = tile * 128;

    // ---- stage A: 16 waves x 8 rows (masked chunk-of-4 gather) ----
    for (int p = 0; p < 2; p++) {
      int row = w * 8 + p * 4 + lg;
      int node = rows0 + row;
      bfrag oh, ol;
      if (node < NN) {
        int beg = rowptr[node], end = rowptr[node + 1];
        float a[8];
        bfrag vs = hp[(size_t)node * 16 + k8v];  // self
#pragma unroll
        for (int j = 0; j < 8; j++) a[j] = b2f((u16)vs[j]);
        for (int i = beg; i < end; i += 4) {
          int last = end - 1;
          int i1 = min(i + 1, last), i2 = min(i + 2, last), i3 = min(i + 3, last);
          int s0 = csr_src[i], s1 = csr_src[i1], s2 = csr_src[i2], s3 = csr_src[i3];
          bfrag v0 = hp[(size_t)s0 * 16 + k8v];
          bfrag v1 = hp[(size_t)s1 * 16 + k8v];
          bfrag v2 = hp[(size_t)s2 * 16 + k8v];
          bfrag v3 = hp[(size_t)s3 * 16 + k8v];
          int rem = end - i;
          float m1 = rem > 1 ? 1.f : 0.f, m2 = rem > 2 ? 1.f : 0.f, m3 = rem > 3 ? 1.f : 0.f;
#pragma unroll
          for (int j = 0; j < 8; j++)
            a[j] += (b2f((u16)v0[j]) + m1 * b2f((u16)v1[j])) +
                    (m2 * b2f((u16)v2[j]) + m3 * b2f((u16)v3[j]));
        }
        float cnt = (float)(end - beg + 1);
#pragma unroll
        for (int j = 0; j < 8; j++) {
          float t = a[j] * sc8[j] + cnt * sh8[j];
          u16 hi, lo;
          split(t, hi, lo);
          oh[j] = (short)hi;
          ol[j] = (short)lo;
        }
      } else {
#pragma unroll
        for (int j = 0; j < 8; j++) { oh[j] = 0; ol[j] = 0; }
      }
      *reinterpret_cast<bfrag*>(&lds[AH + row * 136 + k8]) = oh;
      *reinterpret_cast<bfrag*>(&lds[AL + row * 136 + k8]) = ol;
    }
    // ---- W1 frags for this wave's ct ----
    bfrag w1h[4], w1l[4];
#pragma unroll
    for (int kk = 0; kk < 4; kk++) {
      int fi = ((ct * 4 + kk) * 64 + l) * 8;
      w1h[kk] = *reinterpret_cast<const bfrag*>(&w1hi[fi]);
      w1l[kk] = *reinterpret_cast<const bfrag*>(&w1lo[fi]);
    }
    __syncthreads();  // B1: A staged

    // ---- GEMM1 (accs in regs; A region stays live) ----
    f32x4 t1[4];
#pragma unroll
    for (int rt = 0; rt < 4; rt++) {
      f32x4 acc = {bb1, bb1, bb1, bb1};
      const int arow = (hrow + rt * 16 + l15) * 136 + 8 * lg;
#pragma unroll
      for (int kk = 0; kk < 4; kk++) {
        bfrag ah = *reinterpret_cast<const bfrag*>(&lds[AH + arow + kk * 32]);
        bfrag al = *reinterpret_cast<const bfrag*>(&lds[AL + arow + kk * 32]);
        acc = __builtin_amdgcn_mfma_f32_16x16x32_bf16(al, w1h[kk], acc, 0, 0, 0);
        acc = __builtin_amdgcn_mfma_f32_16x16x32_bf16(ah, w1l[kk], acc, 0, 0, 0);
        acc = __builtin_amdgcn_mfma_f32_16x16x32_bf16(ah, w1h[kk], acc, 0, 0, 0);
      }
      t1[rt] = acc;
    }
    __syncthreads();  // B2: A dead -> region reusable for T

    // ---- write T (relu+split) over A region ----
#pragma unroll
    for (int rt = 0; rt < 4; rt++) {
#pragma unroll
      for (int r = 0; r < 4; r++) {
        float v = fmaxf(t1[rt][r], 0.f);
        u16 hi, lo;
        split(v, hi, lo);
        int off = (hrow + rt * 16 + 4 * lg + r) * 136 + ct * 16 + l15;
        lds[AH + off] = hi;
        lds[AL + off] = lo;
      }
    }
    bfrag w2h[4], w2l[4];
#pragma unroll
    for (int kk = 0; kk < 4; kk++) {
      int fi = ((ct * 4 + kk) * 64 + l) * 8;
      w2h[kk] = *reinterpret_cast<const bfrag*>(&w2hi[fi]);
      w2l[kk] = *reinterpret_cast<const bfrag*>(&w2lo[fi]);
    }
    __syncthreads();  // B3: T visible

    // ---- GEMM2 ----
    u16 o16[16];
#pragma unroll
    for (int rt = 0; rt < 4; rt++) {
      f32x4 acc = {bb2, bb2, bb2, bb2};
      const int arow = (hrow + rt * 16 + l15) * 136 + 8 * lg;
#pragma unroll
      for (int kk = 0; kk < 4; kk++) {
        bfrag th = *reinterpret_cast<const bfrag*>(&lds[AH + arow + kk * 32]);
        bfrag tl = *reinterpret_cast<const bfrag*>(&lds[AL + arow + kk * 32]);
        acc = __builtin_amdgcn_mfma_f32_16x16x32_bf16(tl, w2h[kk], acc, 0, 0, 0);
        acc = __builtin_amdgcn_mfma_f32_16x16x32_bf16(th, w2l[kk], acc, 0, 0, 0);
        acc = __builtin_amdgcn_mfma_f32_16x16x32_bf16(th, w2h[kk], acc, 0, 0, 0);
      }
#pragma unroll
      for (int r = 0; r < 4; r++) {
        float v = fmaxf(acc[r], 0.f);
        int gr = rows0 + hrow + rt * 16 + 4 * lg + r;
        if (gr < NN) {  // tail tile: exclude garbage rows from BN stats
          s_acc += v;
          q_acc += v * v;
        }
        o16[rt * 4 + r] = f2b(v);
      }
    }
    __syncthreads();  // B4: T dead -> region reusable for OUT

    // ---- stage OUT (bf16) ----
#pragma unroll
    for (int rt = 0; rt < 4; rt++)
#pragma unroll
      for (int r = 0; r < 4; r++)
        lds[AH + (hrow + rt * 16 + 4 * lg + r) * 136 + ct * 16 + l15] = o16[rt * 4 + r];
    __syncthreads();  // B5: OUT staged

    // ---- cooperative full-row write: 64 rows/pass x 256B ----
#pragma unroll
    for (int p2 = 0; p2 < 2; p2++) {
      int row = p2 * 64 + (tid >> 4);
      int c8 = tid & 15;
      int gr = rows0 + row;
      if (gr < NN) {
        bfrag vv = *reinterpret_cast<const bfrag*>(&lds[AH + row * 136 + c8 * 8]);
        *reinterpret_cast<bfrag*>(&hout[(size_t)gr * 128 + c8 * 8]) = vv;
      }
    }
    __syncthreads();  // B6: protect region before next staging
  }
  // ---- flush BN stats (2 waves per ct -> 2 atomics per ct) ----
  s_acc += __shfl_xor(s_acc, 16);
  s_acc += __shfl_xor(s_acc, 32);
  q_acc += __shfl_xor(q_acc, 16);
  q_acc += __shfl_xor(q_acc, 32);
  if (lg == 0) {
    atomicAdd(&stats[ct * 16 + l15], s_acc);
    atomicAdd(&stats[128 + ct * 16 + l15], q_acc);
  }
}

// ---------------- BN finalize -------------------------------------------
__global__ void bn_kernel(const float* __restrict__ stats, const float* __restrict__ gamma,
                          const float* __restrict__ beta, float* __restrict__ ss) {
  int c = threadIdx.x;  // 128 threads
  float mean = stats[c] * (1.f / NN);
  float var = stats[128 + c] * (1.f / NN) - mean * mean;
  var = fmaxf(var, 0.f);
  float sc = gamma[c] * rsqrtf(var + 1e-5f);
  ss[c] = sc;
  ss[128 + c] = beta[c] - mean * sc;
}

// ---------------- pooling: run-based segmented sum (batch is sorted) ------
__global__ void pool_kernel(const u16* __restrict__ h, const float* __restrict__ ss,
                            const int* __restrict__ batch, float* __restrict__ pooled) {
  int c = threadIdx.x;  // 128 threads, one feature each
  int n0 = blockIdx.x * 128;
  int n1 = min(n0 + 128, NN);
  float sc = ss[c], sh = ss[128 + c];
  float acc = 0.f;
  float cnt = 0.f;
  int gprev = batch[n0];
  for (int n = n0; n < n1; n++) {
    int g = batch[n];
    if (g != gprev) {
      atomicAdd(&pooled[gprev * 128 + c], sc * acc + cnt * sh);
      acc = 0.f;
      cnt = 0.f;
      gprev = g;
    }
    acc += b2f(h[(size_t)n * 128 + c]);
    cnt += 1.f;
  }
  atomicAdd(&pooled[gprev * 128 + c], sc * acc + cnt * sh);
}

// ---------------- final FC ------------------------------------------------
__global__ void fc_kernel(const float* __restrict__ pooled, const float* __restrict__ fcW,
                          const float* __restrict__ fcb, float* __restrict__ out) {
  int i = blockIdx.x * 256 + threadIdx.x;
  if (i >= NG * 64) return;
  int g = i >> 6, o = i & 63;
  float acc = fcb[o];
#pragma unroll 8
  for (int k = 0; k < 128; k++) acc += pooled[g * 128 + k] * fcW[k * 64 + o];
  out[i] = fmaxf(acc, 0.f);
}

extern "C" void kernel_launch(void* const* d_in, const int* in_sizes, int n_in,
                              void* d_out, int out_size, void* d_ws, size_t ws_size,
                              hipStream_t stream) {
  const float* x = (const float*)d_in[0];
  const int* ei = (const int*)d_in[1];
  const int* src = ei;
  const int* dst = ei + NE;
  const int* batch = (const int*)d_in[2];
  const float* W1_0 = (const float*)d_in[3];
  const float* b1_0 = (const float*)d_in[4];
  const float* W2_0 = (const float*)d_in[5];
  const float* b2_0 = (const float*)d_in[6];
  const float* g_0 = (const float*)d_in[7];
  const float* be_0 = (const float*)d_in[8];
  const float* W1s = (const float*)d_in[9];
  const float* b1s = (const float*)d_in[10];
  const float* W2s = (const float*)d_in[11];
  const float* b2s = (const float*)d_in[12];
  const float* gs = (const float*)d_in[13];
  const float* bes = (const float*)d_in[14];
  const float* fcW = (const float*)d_in[15];
  const float* fcb = (const float*)d_in[16];

  char* ws = (char*)d_ws;
  u16* buf0 = (u16*)(ws + 0);                       // 51,200,000 B
  u16* buf1 = (u16*)(ws + 51200000);                // 51,200,000 B
  float* POOLED = (float*)(ws + 102400000);         // 5,120,000 B
  float* STATS = (float*)(ws + 107520000);          // 1,024 B
  float* SS = (float*)(ws + 107521024);             // 1,024 B
  u16* WF = (u16*)(ws + 107522048);                 // 638,976 B
  int* ROWPTR = (int*)(ws + 108161024);             // 800,016 B
  int* CURSOR = (int*)(ws + 108961040);             // 800,000 B (also deg scratch)
  int* CSRC = (int*)(ws + 109761040);               // 2,400,000 B
  int* CSUM = (int*)(ws + 112161040);               // 512 B

  prep_kernel<<<78, 256, 0, stream>>>(W1_0, W2_0, W1s, W2s, WF);

  // ---- CSR build (once per launch; reused by all 5 layers) ----
  hipMemsetAsync(CURSOR, 0, NN * 4, stream);
  hist_kernel<<<(NE + 255) / 256, 256, 0, stream>>>(dst, CURSOR);
  scan1_kernel<<<NCH, 256, 0, stream>>>(CURSOR, CSUM);
  scan2_kernel<<<1, 1, 0, stream>>>(CSUM, ROWPTR);
  scan3_kernel<<<NCH, 256, 0, stream>>>(CURSOR, CSUM, ROWPTR, CURSOR);
  scatter_kernel<<<(NE + 255) / 256, 256, 0, stream>>>(src, dst, CURSOR, CSRC);

  u16* buf[2] = {buf0, buf1};
  // ---- layer 0: x -> buf0 ----
  hipMemsetAsync(STATS, 0, 1024, stream);
  first_kernel<<<512, 512, 0, stream>>>(x, ROWPTR, CSRC,
                                        WF, WF + 12288, WF + 24576, WF + 40960,
                                        b1_0, b2_0, buf0, STATS);
  bn_kernel<<<1, 128, 0, stream>>>(STATS, g_0, be_0, SS);

  // ---- layers 1..4: ping-pong buf0 <-> buf1 ----
  for (int L = 1; L < 5; L++) {
    int j = L - 1;
    const u16* hin = buf[(L + 1) & 1];
    u16* hb = buf[L & 1];
    hipMemsetAsync(STATS, 0, 1024, stream);
    const u16* wl = WF + 57344 + j * 65536;
    gin_kernel<<<512, 1024, 0, stream>>>(hin, SS, ROWPTR, CSRC,
                                         wl, wl + 16384, wl + 32768, wl + 49152,
                                         b1s + j * 128, b2s + j * 128, hb, STATS);
    bn_kernel<<<1, 128, 0, stream>>>(STATS, gs + j * 128, bes + j * 128, SS);
  }

  hipMemsetAsync(POOLED, 0, (size_t)NG * 128 * 4, stream);
  pool_kernel<<<(NN + 127) / 128, 128, 0, stream>>>(buf[0], SS, batch, POOLED);
  fc_kernel<<<(NG * 64 + 255) / 256, 256, 0, stream>>>(POOLED, fcW, fcb, (float*)d_out);
}

// Round 16
// 668.171 us; speedup vs baseline: 1.9104x; 1.2429x over previous
//
#include <hip/hip_runtime.h>
#include <hip/hip_bf16.h>

#define NN 200000
#define NE 600000
#define NG 10000
#define NCH 98     // scan chunks of 2048 covering NN
#define NTILE 3125 // 64-row tiles

typedef __attribute__((ext_vector_type(8))) short bfrag;
typedef __attribute__((ext_vector_type(4))) float f32x4;
typedef unsigned short u16;

static __device__ __forceinline__ u16 f2b(float x) {
  __hip_bfloat16 b = __float2bfloat16(x);
  return __builtin_bit_cast(u16, b);
}
static __device__ __forceinline__ float b2f(u16 u) {
  __hip_bfloat16 b = __builtin_bit_cast(__hip_bfloat16, u);
  return __bfloat162float(b);
}
static __device__ __forceinline__ void split(float v, u16& hi, u16& lo) {
  hi = f2b(v);
  lo = f2b(v - b2f(hi));
}

// ---------------- weight prep: per-lane MFMA B-fragments, bf16 hi+lo ------
__global__ void prep_kernel(const float* __restrict__ W1_0, const float* __restrict__ W2_0,
                            const float* __restrict__ W1s, const float* __restrict__ W2s,
                            u16* __restrict__ wf) {
  int i = blockIdx.x * 256 + threadIdx.x;
  if (i >= 312 * 64) return;
  int t = i >> 6, lane = i & 63;
  const float* W;
  int KS, ct, kk, Krows, base, half;
  if (t < 24) {
    W = W1_0; KS = 3; ct = t / 3; kk = t - ct * 3; Krows = 78; base = 0; half = 12288;
  } else if (t < 56) {
    int u = t - 24;
    W = W2_0; KS = 4; ct = u >> 2; kk = u & 3; Krows = 128; base = 24576; half = 16384;
  } else {
    int u = t - 56;
    int j = u >> 6, r = u & 63;
    KS = 4; Krows = 128; half = 16384;
    if (r < 32) {
      W = W1s + j * 16384; ct = r >> 2; kk = r & 3; base = 57344 + j * 65536;
    } else {
      W = W2s + j * 16384; r -= 32; ct = r >> 2; kk = r & 3; base = 57344 + j * 65536 + 32768;
    }
  }
  int col = ct * 16 + (lane & 15);
  int idx = ((ct * KS + kk) * 64 + lane) * 8;
  for (int jj = 0; jj < 8; jj++) {
    int k = kk * 32 + 8 * (lane >> 4) + jj;
    float v = (k < Krows) ? W[k * 128 + col] : 0.f;
    u16 hi, lo;
    split(v, hi, lo);
    wf[base + idx + jj] = hi;
    wf[base + half + idx + jj] = lo;
  }
}

// ---------------- CSR build: histogram + scan + scatter -------------------
__global__ void hist_kernel(const int* __restrict__ dst, int* __restrict__ deg) {
  int e = blockIdx.x * 256 + threadIdx.x;
  if (e < NE) atomicAdd(&deg[dst[e]], 1);
}

__global__ void scan1_kernel(const int* __restrict__ deg, int* __restrict__ csum) {
  __shared__ int s[256];
  int base = blockIdx.x * 2048 + threadIdx.x * 8;
  int t = 0;
#pragma unroll
  for (int j = 0; j < 8; j++) {
    int idx = base + j;
    if (idx < NN) t += deg[idx];
  }
  s[threadIdx.x] = t;
  __syncthreads();
  for (int o = 128; o > 0; o >>= 1) {
    if (threadIdx.x < o) s[threadIdx.x] += s[threadIdx.x + o];
    __syncthreads();
  }
  if (threadIdx.x == 0) csum[blockIdx.x] = s[0];
}

__global__ void scan2_kernel(int* __restrict__ csum, int* __restrict__ rowptr) {
  int acc = 0;
  for (int i = 0; i < NCH; i++) {
    int v = csum[i];
    csum[i] = acc;
    acc += v;
  }
  rowptr[NN] = acc;  // == NE
}

// NOTE: deg and cursor may alias (each index read-then-written by one thread).
__global__ void scan3_kernel(const int* deg, const int* __restrict__ csum,
                             int* __restrict__ rowptr, int* cursor) {
  __shared__ int s[256];
  int tid = threadIdx.x;
  int base = blockIdx.x * 2048 + tid * 8;
  int loc[8];
  int t = 0;
#pragma unroll
  for (int j = 0; j < 8; j++) {
    int idx = base + j;
    int d = (idx < NN) ? deg[idx] : 0;
    loc[j] = t;
    t += d;
  }
  s[tid] = t;
  __syncthreads();
  for (int o = 1; o < 256; o <<= 1) {
    int u = (tid >= o) ? s[tid - o] : 0;
    __syncthreads();
    s[tid] += u;
    __syncthreads();
  }
  int off = csum[blockIdx.x] + s[tid] - t;
#pragma unroll
  for (int j = 0; j < 8; j++) {
    int idx = base + j;
    if (idx < NN) {
      int r = off + loc[j];
      rowptr[idx] = r;
      cursor[idx] = r;
    }
  }
}

__global__ void scatter_kernel(const int* __restrict__ src, const int* __restrict__ dst,
                               int* __restrict__ cursor, int* __restrict__ csr_src) {
  int e = blockIdx.x * 256 + threadIdx.x;
  if (e < NE) {
    int p = atomicAdd(&cursor[dst[e]], 1);
    csr_src[p] = src[e];
  }
}

// ---------------- fused GIN block: gather + 2x split-MFMA GEMM + stats ----
// 64-row tiles, 512 threads (8 waves). LDS = one 34.8 KB region, time-
// multiplexed A -> T -> OUT (GEMM1 accs live in regs across the swap).
// Gather: masked chunk-of-4 so all neighbor row-loads are in flight
// (deg<=4 = one parallel round). Output via cooperative full-row writes.
// Grid MUST stay at 512 (2 blocks/CU): higher residency amplifies L2
// traffic 2-4x (R7/R8/R15 measured: the traffic/BW frontier is monotone
// worse past this point). Grid-stride; BN stats in registers.
// hout must NOT alias hin (gather reads arbitrary hin rows).
template <bool FIRST>
__global__ __launch_bounds__(512, 4) void fused_kernel(
    const float* __restrict__ xin, const u16* __restrict__ hin,
    const float* __restrict__ ss,
    const int* __restrict__ rowptr, const int* __restrict__ csr_src,
    const u16* __restrict__ w1hi, const u16* __restrict__ w1lo,
    const u16* __restrict__ w2hi, const u16* __restrict__ w2lo,
    const float* __restrict__ b1, const float* __restrict__ b2,
    u16* __restrict__ hout, float* __restrict__ stats) {
  constexpr int KS1 = FIRST ? 3 : 4;
  constexpr int XH = 0, XL = 8704;  // u16 offsets; 64 rows x 136 each
  __shared__ u16 lds[17408];        // 34,816 B
  const int tid = threadIdx.x;
  const int w = tid >> 6, l = tid & 63;
  const int l15 = l & 15, lg = l >> 4;
  const float bb1 = b1[w * 16 + l15];
  const float bb2 = b2[w * 16 + l15];
  float s_acc = 0.f, q_acc = 0.f;

  // per-lane BN affine constants for staging (fixed layout across tiles)
  float sc8[8], sh8[8];
  if (!FIRST) {
    int k8 = l15 * 8;
#pragma unroll
    for (int j = 0; j < 8; j++) {
      sc8[j] = ss[k8 + j];
      sh8[j] = ss[128 + k8 + j];
    }
  }

  for (int tile = blockIdx.x; tile < NTILE; tile += gridDim.x) {
    const int rows0 = tile * 64;

    // ---- stage A = self + sum(neighbors), BN-affine, split to hi/lo ----
    if (FIRST) {
      // x is f32 [NN][78]; float2 per lane, one row per wave-pass
      const float2* x2 = reinterpret_cast<const float2*>(xin);
      for (int j = 0; j < 8; j++) {
        int row = w * 8 + j;
        int node = rows0 + row;
        int beg = rowptr[node], end = rowptr[node + 1];
        int f0 = l * 2;
        if (f0 < 78) {
          size_t fv = (size_t)(f0 >> 1);
          float2 acc = x2[(size_t)node * 39 + fv];
          for (int i = beg; i < end; i += 4) {
            int last = end - 1;
            int i1 = min(i + 1, last), i2 = min(i + 2, last), i3 = min(i + 3, last);
            int s0 = csr_src[i], s1 = csr_src[i1], s2 = csr_src[i2], s3 = csr_src[i3];
            float2 v0 = x2[(size_t)s0 * 39 + fv];
            float2 v1 = x2[(size_t)s1 * 39 + fv];
            float2 v2 = x2[(size_t)s2 * 39 + fv];
            float2 v3 = x2[(size_t)s3 * 39 + fv];
            int rem = end - i;
            float m1 = rem > 1 ? 1.f : 0.f, m2 = rem > 2 ? 1.f : 0.f, m3 = rem > 3 ? 1.f : 0.f;
            acc.x += v0.x + m1 * v1.x + m2 * v2.x + m3 * v3.x;
            acc.y += v0.y + m1 * v1.y + m2 * v2.y + m3 * v3.y;
          }
          ushort2 oh, ol;
          split(acc.x, oh.x, ol.x);
          split(acc.y, oh.y, ol.y);
          *reinterpret_cast<ushort2*>(&lds[XH + row * 136 + f0]) = oh;
          *reinterpret_cast<ushort2*>(&lds[XL + row * 136 + f0]) = ol;
        } else if (f0 < 96) {
          ushort2 z = {0, 0};
          *reinterpret_cast<ushort2*>(&lds[XH + row * 136 + f0]) = z;
          *reinterpret_cast<ushort2*>(&lds[XL + row * 136 + f0]) = z;
        }
      }
    } else {
      // h is bf16 [NN][128]; 16-lane row groups, ushort8 (16B) per lane;
      // masked chunk-of-4: 4 neighbor row-loads in flight per round
      const bfrag* hp = reinterpret_cast<const bfrag*>(hin);
      const int k8v = l15;
      for (int p = 0; p < 2; p++) {
        int row = w * 8 + p * 4 + lg;
        int node = rows0 + row;
        int beg = rowptr[node], end = rowptr[node + 1];
        float a[8];
        bfrag vs = hp[(size_t)node * 16 + k8v];  // self
#pragma unroll
        for (int j = 0; j < 8; j++) a[j] = b2f((u16)vs[j]);
        for (int i = beg; i < end; i += 4) {
          int last = end - 1;
          int i1 = min(i + 1, last), i2 = min(i + 2, last), i3 = min(i + 3, last);
          int s0 = csr_src[i], s1 = csr_src[i1], s2 = csr_src[i2], s3 = csr_src[i3];
          bfrag v0 = hp[(size_t)s0 * 16 + k8v];
          bfrag v1 = hp[(size_t)s1 * 16 + k8v];
          bfrag v2 = hp[(size_t)s2 * 16 + k8v];
          bfrag v3 = hp[(size_t)s3 * 16 + k8v];
          int rem = end - i;
          float m1 = rem > 1 ? 1.f : 0.f, m2 = rem > 2 ? 1.f : 0.f, m3 = rem > 3 ? 1.f : 0.f;
#pragma unroll
          for (int j = 0; j < 8; j++)
            a[j] += (b2f((u16)v0[j]) + m1 * b2f((u16)v1[j])) +
                    (m2 * b2f((u16)v2[j]) + m3 * b2f((u16)v3[j]));
        }
        float cnt = (float)(end - beg + 1);
        bfrag oh, ol;
#pragma unroll
        for (int j = 0; j < 8; j++) {
          float t = a[j] * sc8[j] + cnt * sh8[j];
          u16 hi, lo;
          split(t, hi, lo);
          oh[j] = (short)hi;
          ol[j] = (short)lo;
        }
        *reinterpret_cast<bfrag*>(&lds[XH + row * 136 + l15 * 8]) = oh;
        *reinterpret_cast<bfrag*>(&lds[XL + row * 136 + l15 * 8]) = ol;
      }
    }
    // ---- W1 frags for this wave's col-tile ----
    bfrag w1h[KS1], w1l[KS1];
#pragma unroll
    for (int kk = 0; kk < KS1; kk++) {
      int fi = ((w * KS1 + kk) * 64 + l) * 8;
      w1h[kk] = *reinterpret_cast<const bfrag*>(&w1hi[fi]);
      w1l[kk] = *reinterpret_cast<const bfrag*>(&w1lo[fi]);
    }
    __syncthreads();

    // ---- GEMM1: T[:, ct] = relu(A @ W1[:, ct] + b1); accs held in regs ----
    f32x4 t1[4];
#pragma unroll
    for (int rt = 0; rt < 4; rt++) {
      f32x4 acc = {bb1, bb1, bb1, bb1};
      const int arow = (rt * 16 + l15) * 136 + 8 * lg;
#pragma unroll
      for (int kk = 0; kk < KS1; kk++) {
        bfrag ah = *reinterpret_cast<const bfrag*>(&lds[XH + arow + kk * 32]);
        bfrag al = *reinterpret_cast<const bfrag*>(&lds[XL + arow + kk * 32]);
        acc = __builtin_amdgcn_mfma_f32_16x16x32_bf16(al, w1h[kk], acc, 0, 0, 0);
        acc = __builtin_amdgcn_mfma_f32_16x16x32_bf16(ah, w1l[kk], acc, 0, 0, 0);
        acc = __builtin_amdgcn_mfma_f32_16x16x32_bf16(ah, w1h[kk], acc, 0, 0, 0);
      }
      t1[rt] = acc;
    }
    __syncthreads();  // all waves done reading A -> region reusable for T

    // ---- write T (relu+split) into the same region ----
#pragma unroll
    for (int rt = 0; rt < 4; rt++) {
#pragma unroll
      for (int r = 0; r < 4; r++) {
        float v = fmaxf(t1[rt][r], 0.f);
        u16 hi, lo;
        split(v, hi, lo);
        int off = (rt * 16 + 4 * lg + r) * 136 + w * 16 + l15;
        lds[XH + off] = hi;
        lds[XL + off] = lo;
      }
    }
    // ---- W2 frags ----
    bfrag w2h[4], w2l[4];
#pragma unroll
    for (int kk = 0; kk < 4; kk++) {
      int fi = ((w * 4 + kk) * 64 + l) * 8;
      w2h[kk] = *reinterpret_cast<const bfrag*>(&w2hi[fi]);
      w2l[kk] = *reinterpret_cast<const bfrag*>(&w2lo[fi]);
    }
    __syncthreads();

    // ---- GEMM2: U[:, ct] = relu(T @ W2 + b2); outputs held in regs ----
    u16 o16[16];
#pragma unroll
    for (int rt = 0; rt < 4; rt++) {
      f32x4 acc = {bb2, bb2, bb2, bb2};
      const int arow = (rt * 16 + l15) * 136 + 8 * lg;
#pragma unroll
      for (int kk = 0; kk < 4; kk++) {
        bfrag th = *reinterpret_cast<const bfrag*>(&lds[XH + arow + kk * 32]);
        bfrag tl = *reinterpret_cast<const bfrag*>(&lds[XL + arow + kk * 32]);
        acc = __builtin_amdgcn_mfma_f32_16x16x32_bf16(tl, w2h[kk], acc, 0, 0, 0);
        acc = __builtin_amdgcn_mfma_f32_16x16x32_bf16(th, w2l[kk], acc, 0, 0, 0);
        acc = __builtin_amdgcn_mfma_f32_16x16x32_bf16(th, w2h[kk], acc, 0, 0, 0);
      }
#pragma unroll
      for (int r = 0; r < 4; r++) {
        float v = fmaxf(acc[r], 0.f);
        s_acc += v;
        q_acc += v * v;
        o16[rt * 4 + r] = f2b(v);
      }
    }
    __syncthreads();  // all waves done reading T -> region reusable for OUT

    // ---- stage output tile in LDS (bf16, [64][136]) ----
#pragma unroll
    for (int rt = 0; rt < 4; rt++) {
#pragma unroll
      for (int r = 0; r < 4; r++) {
        lds[XH + (rt * 16 + 4 * lg + r) * 136 + w * 16 + l15] = o16[rt * 4 + r];
      }
    }
    __syncthreads();

    // ---- cooperative full-row write: 16 threads x 16B = 256B per row ----
#pragma unroll
    for (int p = 0; p < 2; p++) {
      int row = p * 32 + (tid >> 4);
      int c8 = tid & 15;
      bfrag vv = *reinterpret_cast<const bfrag*>(&lds[XH + row * 136 + c8 * 8]);
      *reinterpret_cast<bfrag*>(&hout[(size_t)(rows0 + row) * 128 + c8 * 8]) = vv;
    }
    __syncthreads();  // protect region before next tile's stage
  }
  // ---- flush BN stats (once per block) ----
  s_acc += __shfl_xor(s_acc, 16);
  s_acc += __shfl_xor(s_acc, 32);
  q_acc += __shfl_xor(q_acc, 16);
  q_acc += __shfl_xor(q_acc, 32);
  if (lg == 0) {
    atomicAdd(&stats[w * 16 + l15], s_acc);
    atomicAdd(&stats[128 + w * 16 + l15], q_acc);
  }
}

// ---------------- BN finalize -------------------------------------------
__global__ void bn_kernel(const float* __restrict__ stats, const float* __restrict__ gamma,
                          const float* __restrict__ beta, float* __restrict__ ss) {
  int c = threadIdx.x;  // 128 threads
  float mean = stats[c] * (1.f / NN);
  float var = stats[128 + c] * (1.f / NN) - mean * mean;
  var = fmaxf(var, 0.f);
  float sc = gamma[c] * rsqrtf(var + 1e-5f);
  ss[c] = sc;
  ss[128 + c] = beta[c] - mean * sc;
}

// ---------------- pooling: run-based segmented sum (batch is sorted) ------
__global__ void pool_kernel(const u16* __restrict__ h, const float* __restrict__ ss,
                            const int* __restrict__ batch, float* __restrict__ pooled) {
  int c = threadIdx.x;  // 128 threads, one feature each
  int n0 = blockIdx.x * 128;
  int n1 = min(n0 + 128, NN);
  float sc = ss[c], sh = ss[128 + c];
  float acc = 0.f;
  float cnt = 0.f;
  int gprev = batch[n0];
  for (int n = n0; n < n1; n++) {
    int g = batch[n];
    if (g != gprev) {
      atomicAdd(&pooled[gprev * 128 + c], sc * acc + cnt * sh);
      acc = 0.f;
      cnt = 0.f;
      gprev = g;
    }
    acc += b2f(h[(size_t)n * 128 + c]);
    cnt += 1.f;
  }
  atomicAdd(&pooled[gprev * 128 + c], sc * acc + cnt * sh);
}

// ---------------- final FC ------------------------------------------------
__global__ void fc_kernel(const float* __restrict__ pooled, const float* __restrict__ fcW,
                          const float* __restrict__ fcb, float* __restrict__ out) {
  int i = blockIdx.x * 256 + threadIdx.x;
  if (i >= NG * 64) return;
  int g = i >> 6, o = i & 63;
  float acc = fcb[o];
#pragma unroll 8
  for (int k = 0; k < 128; k++) acc += pooled[g * 128 + k] * fcW[k * 64 + o];
  out[i] = fmaxf(acc, 0.f);
}

extern "C" void kernel_launch(void* const* d_in, const int* in_sizes, int n_in,
                              void* d_out, int out_size, void* d_ws, size_t ws_size,
                              hipStream_t stream) {
  const float* x = (const float*)d_in[0];
  const int* ei = (const int*)d_in[1];
  const int* src = ei;
  const int* dst = ei + NE;
  const int* batch = (const int*)d_in[2];
  const float* W1_0 = (const float*)d_in[3];
  const float* b1_0 = (const float*)d_in[4];
  const float* W2_0 = (const float*)d_in[5];
  const float* b2_0 = (const float*)d_in[6];
  const float* g_0 = (const float*)d_in[7];
  const float* be_0 = (const float*)d_in[8];
  const float* W1s = (const float*)d_in[9];
  const float* b1s = (const float*)d_in[10];
  const float* W2s = (const float*)d_in[11];
  const float* b2s = (const float*)d_in[12];
  const float* gs = (const float*)d_in[13];
  const float* bes = (const float*)d_in[14];
  const float* fcW = (const float*)d_in[15];
  const float* fcb = (const float*)d_in[16];

  char* ws = (char*)d_ws;
  u16* buf0 = (u16*)(ws + 0);                       // 51,200,000 B
  u16* buf1 = (u16*)(ws + 51200000);                // 51,200,000 B
  float* POOLED = (float*)(ws + 102400000);         // 5,120,000 B
  float* STATS = (float*)(ws + 107520000);          // 1,024 B
  float* SS = (float*)(ws + 107521024);             // 1,024 B
  u16* WF = (u16*)(ws + 107522048);                 // 638,976 B
  int* ROWPTR = (int*)(ws + 108161024);             // 800,016 B
  int* CURSOR = (int*)(ws + 108961040);             // 800,000 B (also deg scratch)
  int* CSRC = (int*)(ws + 109761040);               // 2,400,000 B
  int* CSUM = (int*)(ws + 112161040);               // 512 B

  prep_kernel<<<78, 256, 0, stream>>>(W1_0, W2_0, W1s, W2s, WF);

  // ---- CSR build (once per launch; reused by all 5 layers) ----
  hipMemsetAsync(CURSOR, 0, NN * 4, stream);
  hist_kernel<<<(NE + 255) / 256, 256, 0, stream>>>(dst, CURSOR);
  scan1_kernel<<<NCH, 256, 0, stream>>>(CURSOR, CSUM);
  scan2_kernel<<<1, 1, 0, stream>>>(CSUM, ROWPTR);
  scan3_kernel<<<NCH, 256, 0, stream>>>(CURSOR, CSUM, ROWPTR, CURSOR);
  scatter_kernel<<<(NE + 255) / 256, 256, 0, stream>>>(src, dst, CURSOR, CSRC);

  u16* buf[2] = {buf0, buf1};
  // ---- layer 0: x -> buf0 ----
  hipMemsetAsync(STATS, 0, 1024, stream);
  fused_kernel<true><<<512, 512, 0, stream>>>(x, nullptr, nullptr, ROWPTR, CSRC,
                                              WF, WF + 12288, WF + 24576, WF + 40960,
                                              b1_0, b2_0, buf0, STATS);
  bn_kernel<<<1, 128, 0, stream>>>(STATS, g_0, be_0, SS);

  // ---- layers 1..4: ping-pong buf0 <-> buf1 ----
  for (int L = 1; L < 5; L++) {
    int j = L - 1;
    const u16* hin = buf[(L + 1) & 1];
    u16* hb = buf[L & 1];
    hipMemsetAsync(STATS, 0, 1024, stream);
    const u16* wl = WF + 57344 + j * 65536;
    fused_kernel<false><<<512, 512, 0, stream>>>(nullptr, hin, SS, ROWPTR, CSRC,
                                                 wl, wl + 16384, wl + 32768, wl + 49152,
                                                 b1s + j * 128, b2s + j * 128, hb, STATS);
    bn_kernel<<<1, 128, 0, stream>>>(STATS, gs + j * 128, bes + j * 128, SS);
  }

  hipMemsetAsync(POOLED, 0, (size_t)NG * 128 * 4, stream);
  pool_kernel<<<(NN + 127) / 128, 128, 0, stream>>>(buf[0], SS, batch, POOLED);
  fc_kernel<<<(NG * 64 + 255) / 256, 256, 0, stream>>>(POOLED, fcW, fcb, (float*)d_out);
}